// Round 12
// baseline (206.427 us; speedup 1.0000x reference)
//
#include <hip/hip_runtime.h>
#include <hip/hip_bf16.h>
#include <stdint.h>

#define BB 32
#define NN 1024
#define CC 1024
#define LL 16

typedef __attribute__((ext_vector_type(4))) float f32x4;
typedef __attribute__((ext_vector_type(8))) short short8;
typedef __attribute__((ext_vector_type(4))) unsigned short ushort4v;

__device__ __forceinline__ unsigned short f2bf(float f) {
  union { float f; unsigned u; } v; v.f = f;
  unsigned r = v.u + 0x7FFF + ((v.u >> 16) & 1);
  return (unsigned short)(r >> 16);
}
__device__ __forceinline__ float bf2f(unsigned short h) {
  union { unsigned u; float f; } v; v.u = ((unsigned)h) << 16; return v.f;
}
__device__ __forceinline__ short8 cvt8(f32x4 a, f32x4 b) {
  short8 r;
  r[0] = (short)f2bf(a[0]); r[1] = (short)f2bf(a[1]);
  r[2] = (short)f2bf(a[2]); r[3] = (short)f2bf(a[3]);
  r[4] = (short)f2bf(b[0]); r[5] = (short)f2bf(b[1]);
  r[6] = (short)f2bf(b[2]); r[7] = (short)f2bf(b[3]);
  return r;
}

// ---------------- weight prep: transpose->bf16 (+ tokW^T, bias pack at z=5) ----------------
__global__ __launch_bounds__(256) void wprep(
    const float* __restrict__ keyW, const float* __restrict__ queryW,
    const float* __restrict__ f1W, const float* __restrict__ f2W,
    const float* __restrict__ kW, const float* __restrict__ qW,
    const float* __restrict__ tokW, const float* __restrict__ keyb,
    const float* __restrict__ queryb,
    unsigned short* __restrict__ WkqT, unsigned short* __restrict__ f1WT,
    unsigned short* __restrict__ f2WT, unsigned short* __restrict__ kWT,
    unsigned short* __restrict__ qWbf, unsigned short* __restrict__ tokWT,
    float* __restrict__ biaskq)
{
  int z = blockIdx.z;
  int tx = threadIdx.x, ty = threadIdx.y;
  if (z == 5) {
    int gid = (blockIdx.y * 32 + blockIdx.x) * 256 + ty * 32 + tx;
    if (gid < 16384) {
      int l = gid >> 10, c = gid & 1023;
      tokWT[gid] = f2bf(tokW[c * 16 + l]);
    } else if (gid < 17408) {
      int i = gid - 16384;
      biaskq[i] = (i < 512) ? keyb[i] : queryb[i - 512];
    }
    return;
  }
  if (z == 4) {
#pragma unroll
    for (int i = 0; i < 4; ++i) {
      int row = blockIdx.y * 32 + ty + 8 * i;
      int col = blockIdx.x * 32 + tx;
      qWbf[row * 1024 + col] = f2bf(qW[row * 1024 + col]);
    }
    return;
  }
  __shared__ float tile[32][33];
  int j0 = blockIdx.x * 32, k0 = blockIdx.y * 32;
  const float* src = (z == 1) ? f1W : (z == 2) ? f2W : kW;
#pragma unroll
  for (int i = 0; i < 4; ++i) {
    int k = k0 + ty + 8 * i;
    int j = j0 + tx;
    float v;
    if (z == 0) v = (j < 512) ? keyW[k * 512 + j] : queryW[k * 512 + (j - 512)];
    else        v = src[k * 1024 + j];
    tile[ty + 8 * i][tx] = v;
  }
  __syncthreads();
  unsigned short* dst = (z == 0) ? WkqT : (z == 1) ? f1WT : (z == 2) ? f2WT : kWT;
#pragma unroll
  for (int i = 0; i < 4; ++i) {
    int j = j0 + ty + 8 * i;
    dst[j * 1024 + k0 + tx] = f2bf(tile[tx][ty + 8 * i]);
  }
}

// ---------------- fused tokenizer: 512 thr, K-split phase 1, row-split phase 2 ----------------
__global__ __launch_bounds__(512, 4) void tok_fused(
    const float* __restrict__ X, const unsigned short* __restrict__ tokWT,
    const float* __restrict__ tokB, unsigned short* __restrict__ Tp,
    float* __restrict__ Mloc, float* __restrict__ Sloc)
{
  __shared__ float E[64][16];                   // 4 KB
  __shared__ __align__(16) f32x4 accbuf[4][64]; // 4 KB
  __shared__ float redm[4][16], reds[4][16];
  __shared__ __align__(16) ushort4v hbuf[256][16]; // 32 KB
  int tid = threadIdx.x;
  int wid = tid >> 6, lane = tid & 63;
  int lr = lane & 15, hi = lane >> 4;
  int rowgrp = wid & 3, khalf = wid >> 2;
  int b = blockIdx.y, ch = blockIdx.x;
  int pix0 = b * 1024 + ch * 64;
  // phase 1: S = X @ tokW^T, 8 waves = 4 row-groups x 2 K-halves
  const float* Ar = X + (size_t)(pix0 + rowgrp * 16 + lr) * 1024 + khalf * 512 + hi * 8;
  const unsigned short* Br = tokWT + lr * 1024 + khalf * 512 + hi * 8;
  f32x4 acc = (f32x4)0.f;
#pragma unroll 8
  for (int k0 = 0; k0 < 512; k0 += 32) {
    f32x4 x0 = *(const f32x4*)(Ar + k0);
    f32x4 x1 = *(const f32x4*)(Ar + k0 + 4);
    short8 bfrag = *(const short8*)(Br + k0);
    acc = __builtin_amdgcn_mfma_f32_16x16x32_bf16(cvt8(x0, x1), bfrag, acc, 0, 0, 0);
  }
  if (khalf == 1) accbuf[rowgrp][lane] = acc;
  __syncthreads();
  float tb = tokB[lr];
  float sv[4];
  if (khalf == 0) {
    f32x4 other = accbuf[rowgrp][lane];
#pragma unroll
    for (int rr = 0; rr < 4; ++rr) sv[rr] = acc[rr] + other[rr] + tb;
    float pm = fmaxf(fmaxf(sv[0], sv[1]), fmaxf(sv[2], sv[3]));
    pm = fmaxf(pm, __shfl_xor(pm, 16));
    pm = fmaxf(pm, __shfl_xor(pm, 32));
    if (hi == 0) redm[rowgrp][lr] = pm;
  }
  __syncthreads();
  if (khalf == 0) {
    float m = fmaxf(fmaxf(redm[0][lr], redm[1][lr]), fmaxf(redm[2][lr], redm[3][lr]));
    float ev[4]; float ps = 0.f;
#pragma unroll
    for (int i = 0; i < 4; ++i) { ev[i] = __expf(sv[i] - m); ps += ev[i]; }
    ps += __shfl_xor(ps, 16); ps += __shfl_xor(ps, 32);
    if (hi == 0) reds[rowgrp][lr] = ps;
#pragma unroll
    for (int rr = 0; rr < 4; ++rr)
      E[rowgrp * 16 + hi * 4 + rr][lr] = ev[rr];
  }
  __syncthreads();
  if (tid < 16) {
    float m2 = fmaxf(fmaxf(redm[0][tid], redm[1][tid]), fmaxf(redm[2][tid], redm[3][tid]));
    float sl = reds[0][tid] + reds[1][tid] + reds[2][tid] + reds[3][tid];
    Mloc[(b * 16 + ch) * 16 + tid] = m2;
    Sloc[(b * 16 + ch) * 16 + tid] = sl;
  }
  // phase 2: partial T[l][c] = sum_n E[n][l]*X[n][c]; halves split rows, combine via LDS bf16
  int half = tid >> 8, tn = tid & 255;
  int c4 = tn * 4;
  f32x4 a16[16];
#pragma unroll
  for (int l = 0; l < 16; ++l) a16[l] = (f32x4)0.f;
  const float* xp = X + (size_t)(pix0 + half * 32) * 1024 + c4;
  for (int n0 = 0; n0 < 32; n0 += 8) {
    f32x4 xv[8];
#pragma unroll
    for (int i = 0; i < 8; ++i) xv[i] = *(const f32x4*)(xp + (size_t)(n0 + i) * 1024);
#pragma unroll
    for (int i = 0; i < 8; ++i) {
      const f32x4* ar = (const f32x4*)&E[half * 32 + n0 + i][0];
      f32x4 a0 = ar[0], a1 = ar[1], a2 = ar[2], a3 = ar[3];
      f32x4 x0 = xv[i];
      a16[0]  += a0[0]*x0; a16[1]  += a0[1]*x0; a16[2]  += a0[2]*x0; a16[3]  += a0[3]*x0;
      a16[4]  += a1[0]*x0; a16[5]  += a1[1]*x0; a16[6]  += a1[2]*x0; a16[7]  += a1[3]*x0;
      a16[8]  += a2[0]*x0; a16[9]  += a2[1]*x0; a16[10] += a2[2]*x0; a16[11] += a2[3]*x0;
      a16[12] += a3[0]*x0; a16[13] += a3[1]*x0; a16[14] += a3[2]*x0; a16[15] += a3[3]*x0;
    }
  }
  if (half == 1) {
#pragma unroll
    for (int l = 0; l < 16; ++l) {
      f32x4 s = a16[l];
      ushort4v h; h[0]=f2bf(s[0]); h[1]=f2bf(s[1]); h[2]=f2bf(s[2]); h[3]=f2bf(s[3]);
      hbuf[tn][l] = h;
    }
  }
  __syncthreads();
  if (half == 0) {
    unsigned short* op = Tp + ((size_t)(b * 16 + ch) * 16) * 1024 + c4;
#pragma unroll
    for (int l = 0; l < 16; ++l) {
      ushort4v hv = hbuf[tn][l];
      f32x4 s = a16[l];
      s[0] += bf2f(hv[0]); s[1] += bf2f(hv[1]);
      s[2] += bf2f(hv[2]); s[3] += bf2f(hv[3]);
      ushort4v h; h[0]=f2bf(s[0]); h[1]=f2bf(s[1]); h[2]=f2bf(s[2]); h[3]=f2bf(s[3]);
      *(ushort4v*)(op + (size_t)l * 1024) = h;
    }
  }
}

// ---------------- merge 16 chunk partials with online-softmax rescale ----------------
__global__ __launch_bounds__(256) void tmerge(
    const unsigned short* __restrict__ Tp, const float* __restrict__ Mloc,
    const float* __restrict__ Sloc, float* __restrict__ T,
    unsigned short* __restrict__ Tbf)
{
  int tid = threadIdx.x;
  int g = blockIdx.x * 2 + (tid >> 7);    // token row in [0,512)
  int b = g >> 4, l = g & 15;
  int j = tid & 127;
  float M = -1e30f;
#pragma unroll
  for (int ch = 0; ch < 16; ++ch) M = fmaxf(M, Mloc[(b * 16 + ch) * 16 + l]);
  float w[16]; float denom = 0.f;
#pragma unroll
  for (int ch = 0; ch < 16; ++ch) {
    w[ch] = __expf(Mloc[(b * 16 + ch) * 16 + l] - M);
    denom += w[ch] * Sloc[(b * 16 + ch) * 16 + l];
  }
  float inv = 1.f / denom;
  float o[8];
#pragma unroll
  for (int t = 0; t < 8; ++t) o[t] = 0.f;
#pragma unroll
  for (int ch = 0; ch < 16; ++ch) {
    const unsigned short* p = Tp + ((size_t)((b * 16 + ch) * 16 + l)) * 1024 + j * 8;
    short8 v = *(const short8*)p;
    float wc = w[ch];
#pragma unroll
    for (int t = 0; t < 8; ++t) o[t] += wc * bf2f((unsigned short)v[t]);
  }
  f32x4 o0, o1; short8 hb;
#pragma unroll
  for (int t = 0; t < 4; ++t) {
    float x0 = o[t] * inv, x1 = o[4 + t] * inv;
    o0[t] = x0; o1[t] = x1;
    hb[t] = (short)f2bf(x0); hb[4 + t] = (short)f2bf(x1);
  }
  *(f32x4*)(T + (size_t)g * 1024 + j * 8) = o0;
  *(f32x4*)(T + (size_t)g * 1024 + j * 8 + 4) = o1;
  *(short8*)(Tbf + (size_t)g * 1024 + j * 8) = hb;
}

// ---------------- NT bf16 GEMM, 32x64 tiles, depth-4 register prefetch ----------------
template<int RELU, int HAS_BIAS, int HAS_RES, int STORE_F32, int STORE_BF16>
__global__ __launch_bounds__(256) void gemm32x64(
    const unsigned short* __restrict__ A, const unsigned short* __restrict__ Bm,
    const float* __restrict__ bias, const float* __restrict__ res,
    float* __restrict__ outF, unsigned short* __restrict__ outB)
{
  const int K = 1024;
  __shared__ __align__(16) char sh[12288];
  char* Asp = sh;
  char* Bsp = sh + 4096;
  int tid = threadIdx.x, wid = tid >> 6, lane = tid & 63;
  int lr = lane & 15, hi = lane >> 4;
  int m0 = blockIdx.x * 32, n0 = blockIdx.y * 64;
  int arow = tid >> 3, acol = (tid & 7) * 8;
  int brow = tid >> 2, bcol = (tid & 3) * 16;
  const unsigned short* Ap = A + (size_t)(m0 + arow) * K + acol;
  const unsigned short* Bp = Bm + (size_t)(n0 + brow) * K + bcol;
  int aw  = arow * 128 + (((acol * 2) ^ ((arow & 7) << 4)));
  int bw0 = brow * 128 + (((bcol * 2) ^ ((brow & 7) << 4)));
  int bw1 = brow * 128 + ((((bcol * 2) + 16) ^ ((brow & 7) << 4)));
  short8 aR[4]; short8 bR[4][2];
#pragma unroll
  for (int p = 0; p < 4; ++p) {
    aR[p]    = *(const short8*)(Ap + p * 64);
    bR[p][0] = *(const short8*)(Bp + p * 64);
    bR[p][1] = *(const short8*)(Bp + p * 64 + 8);
  }
  f32x4 acc[2];
  acc[0] = (f32x4)0.f; acc[1] = (f32x4)0.f;
  int wm = (wid >> 1) * 16, wn = (wid & 1) * 32;
  int arb = (wm + lr) * 128, arx = ((wm + lr) & 7) << 4;
  for (int s = 0; s < 16; ++s) {
    __syncthreads();
    *(short8*)(Asp + aw)  = aR[s & 3];
    *(short8*)(Bsp + bw0) = bR[s & 3][0];
    *(short8*)(Bsp + bw1) = bR[s & 3][1];
    __syncthreads();
    if (s + 4 < 16) {
      int k0 = (s + 4) * 64;
      aR[s & 3]    = *(const short8*)(Ap + k0);
      bR[s & 3][0] = *(const short8*)(Bp + k0);
      bR[s & 3][1] = *(const short8*)(Bp + k0 + 8);
    }
#pragma unroll
    for (int kk = 0; kk < 2; ++kk) {
      short8 af = *(const short8*)(Asp + arb + (((kk * 64 + hi * 16) ^ arx)));
#pragma unroll
      for (int sn = 0; sn < 2; ++sn) {
        int br = wn + sn * 16 + lr;
        short8 bf = *(const short8*)(Bsp + br * 128 + (((kk * 64 + hi * 16) ^ ((br & 7) << 4))));
        acc[sn] = __builtin_amdgcn_mfma_f32_16x16x32_bf16(af, bf, acc[sn], 0, 0, 0);
      }
    }
  }
  int row0 = m0 + wm + hi * 4;
#pragma unroll
  for (int sn = 0; sn < 2; ++sn) {
    int col = n0 + wn + sn * 16 + lr;
    float bv_ = HAS_BIAS ? bias[col] : 0.f;
#pragma unroll
    for (int rr = 0; rr < 4; ++rr) {
      float x = acc[sn][rr] + bv_;
      if (RELU) x = fmaxf(x, 0.f);
      size_t idx = (size_t)(row0 + rr) * 1024 + col;
      if (HAS_RES) x += res[idx];
      if (STORE_F32) outF[idx] = x;
      if (STORE_BF16) outB[idx] = f2bf(x);
    }
  }
}

// ---------------- token self-attn: scores + softmax + T_dash (c-split 8) ----------------
__global__ __launch_bounds__(256) void scores_tdash(
    const float* __restrict__ kq, const float* __restrict__ T,
    float* __restrict__ Tdash, unsigned short* __restrict__ Tdbf)
{
  int cs = blockIdx.x, b = blockIdx.y;
  int c0 = cs * 128;
  __shared__ float Ts[16][128];
  int tid = threadIdx.x, lane = tid & 63;
#pragma unroll
  for (int i = 0; i < 2; ++i) {
    int fi = tid + 256 * i;
    int rrow = fi >> 5, c4 = (fi & 31) * 4;
    *(f32x4*)&Ts[rrow][c4] = *(const f32x4*)&T[((size_t)b * 16 + rrow) * 1024 + c0 + c4];
  }
  __syncthreads();
  int l = tid >> 4, m = tid & 15;
  const float* krow = kq + ((size_t)b * 16 + l) * 1024;
  const float* qrow = kq + ((size_t)b * 16 + m) * 1024 + 512;
  float s = 0.f;
#pragma unroll 8
  for (int d = 0; d < 512; d += 4) {
    f32x4 kv = *(const f32x4*)(krow + d);
    f32x4 qv = *(const f32x4*)(qrow + d);
    s += kv[0]*qv[0] + kv[1]*qv[1] + kv[2]*qv[2] + kv[3]*qv[3];
  }
  float mx = s;
  mx = fmaxf(mx, __shfl_xor(mx, 1)); mx = fmaxf(mx, __shfl_xor(mx, 2));
  mx = fmaxf(mx, __shfl_xor(mx, 4)); mx = fmaxf(mx, __shfl_xor(mx, 8));
  float e = __expf(s - mx);
  float sum = e;
  sum += __shfl_xor(sum, 1); sum += __shfl_xor(sum, 2);
  sum += __shfl_xor(sum, 4); sum += __shfl_xor(sum, 8);
  float pv = e / sum;
  float pl[16];
#pragma unroll
  for (int i = 0; i < 16; ++i) pl[i] = __shfl(pv, (lane & 48) + i);
  float* od = Tdash + ((size_t)b * 16 + l) * 1024 + c0;
  unsigned short* ob = Tdbf + ((size_t)b * 16 + l) * 1024 + c0;
#pragma unroll
  for (int h = 0; h < 2; ++h) {
    int c = m * 8 + h * 4;
    f32x4 o = *(const f32x4*)&Ts[l][c];
#pragma unroll
    for (int mm = 0; mm < 16; ++mm) {
      f32x4 tv = *(const f32x4*)&Ts[mm][c];
      o += pl[mm] * tv;
    }
    *(f32x4*)(od + c) = o;
    ushort4v hh; hh[0]=f2bf(o[0]); hh[1]=f2bf(o[1]); hh[2]=f2bf(o[2]); hh[3]=f2bf(o[3]);
    *(ushort4v*)(ob + c) = hh;
  }
}

// ---------------- r[b,l] = q_b . Tk[b,l,:] ----------------
__global__ __launch_bounds__(256) void r_kernel(
    const unsigned short* __restrict__ Tkbf, const float* __restrict__ qb,
    float* __restrict__ r)
{
  int row = blockIdx.x * 4 + (threadIdx.x >> 6);
  int lane = threadIdx.x & 63;
  const unsigned short* p = Tkbf + (size_t)row * CC;
  float s = 0.f;
#pragma unroll
  for (int h = 0; h < 2; ++h) {
    int d0 = lane * 8 + h * 512;
    short8 v = *(const short8*)&p[d0];
#pragma unroll
    for (int jj = 0; jj < 8; ++jj)
      s += bf2f((unsigned short)v[jj]) * qb[d0 + jj];
  }
#pragma unroll
  for (int msk = 32; msk >= 1; msk >>= 1) s += __shfl_xor(s, msk);
  if (lane == 0) r[row] = s;
}

// ---------------- fused sim + out (512 thr, K-split phase 1, row-split phase 2) ----------------
__global__ __launch_bounds__(512, 4) void sim_out_kernel(
    const float* __restrict__ X, const unsigned short* __restrict__ Gt,
    const float* __restrict__ rbias, const float* __restrict__ Tout,
    float* __restrict__ Xout)
{
  __shared__ float Ps[64][16];
  __shared__ __align__(16) f32x4 accbuf[4][64];
  int tid = threadIdx.x, wid = tid >> 6, lane = tid & 63;
  int lr = lane & 15, hi = lane >> 4;
  int rowgrp = wid & 3, khalf = wid >> 2;
  int b = blockIdx.y;
  int pix0 = b * 1024 + blockIdx.x * 64;
  const float* Ar = X + (size_t)(pix0 + rowgrp * 16 + lr) * 1024 + khalf * 512 + hi * 8;
  const unsigned short* Br = Gt + (size_t)b * 16384 + lr * 1024 + khalf * 512 + hi * 8;
  f32x4 acc = (f32x4)0.f;
#pragma unroll 8
  for (int k0 = 0; k0 < 512; k0 += 32) {
    f32x4 x0 = *(const f32x4*)(Ar + k0);
    f32x4 x1 = *(const f32x4*)(Ar + k0 + 4);
    short8 bfrag = *(const short8*)(Br + k0);
    acc = __builtin_amdgcn_mfma_f32_16x16x32_bf16(cvt8(x0, x1), bfrag, acc, 0, 0, 0);
  }
  if (khalf == 1) accbuf[rowgrp][lane] = acc;
  __syncthreads();
  if (khalf == 0) {
    f32x4 other = accbuf[rowgrp][lane];
    float bv = rbias[b * 16 + lr];
    int prow = rowgrp * 16 + hi * 4;
#pragma unroll
    for (int rr = 0; rr < 4; ++rr) {
      float vv = acc[rr] + other[rr] + bv;
      float mx = vv;
      mx = fmaxf(mx, __shfl_xor(mx, 1)); mx = fmaxf(mx, __shfl_xor(mx, 2));
      mx = fmaxf(mx, __shfl_xor(mx, 4)); mx = fmaxf(mx, __shfl_xor(mx, 8));
      float e = __expf(vv - mx);
      float ss = e;
      ss += __shfl_xor(ss, 1); ss += __shfl_xor(ss, 2);
      ss += __shfl_xor(ss, 4); ss += __shfl_xor(ss, 8);
      Ps[prow + rr][lr] = e / ss;
    }
  }
  __syncthreads();
  // phase 2: X_out = X + P @ T_out; thread-halves take disjoint row ranges
  int half = tid >> 8, tn = tid & 255;
  int c4 = tn * 4;
  f32x4 tsr[16];
#pragma unroll
  for (int l = 0; l < 16; ++l)
    tsr[l] = *(const f32x4*)&Tout[((size_t)b * 16 + l) * 1024 + c4];
  const float* xp = X + (size_t)(pix0 + half * 32) * 1024 + c4;
  float* op = Xout + (size_t)(pix0 + half * 32) * 1024 + c4;
#pragma unroll 2
  for (int n = 0; n < 32; ++n) {
    f32x4 xv = *(const f32x4*)(xp + (size_t)n * 1024);
    const f32x4* pr = (const f32x4*)&Ps[half * 32 + n][0];
    f32x4 p0 = pr[0], p1 = pr[1], p2 = pr[2], p3 = pr[3];
    f32x4 o = xv;
    o += p0[0]*tsr[0];  o += p0[1]*tsr[1];  o += p0[2]*tsr[2];  o += p0[3]*tsr[3];
    o += p1[0]*tsr[4];  o += p1[1]*tsr[5];  o += p1[2]*tsr[6];  o += p1[3]*tsr[7];
    o += p2[0]*tsr[8];  o += p2[1]*tsr[9];  o += p2[2]*tsr[10]; o += p2[3]*tsr[11];
    o += p3[0]*tsr[12]; o += p3[1]*tsr[13]; o += p3[2]*tsr[14]; o += p3[3]*tsr[15];
    __builtin_nontemporal_store(o, (f32x4*)(op + (size_t)n * 1024));
  }
}

extern "C" void kernel_launch(void* const* d_in, const int* in_sizes, int n_in,
                              void* d_out, int out_size, void* d_ws, size_t ws_size,
                              hipStream_t stream)
{
  const float* X      = (const float*)d_in[0];
  const float* tokW   = (const float*)d_in[2];
  const float* tokB   = (const float*)d_in[3];
  const float* keyW   = (const float*)d_in[4];
  const float* keyB   = (const float*)d_in[5];
  const float* queryW = (const float*)d_in[6];
  const float* queryB = (const float*)d_in[7];
  const float* f1W    = (const float*)d_in[8];
  const float* f1B    = (const float*)d_in[9];
  const float* f2W    = (const float*)d_in[10];
  const float* f2B    = (const float*)d_in[11];
  const float* qW     = (const float*)d_in[12];
  const float* qB     = (const float*)d_in[13];
  const float* kW     = (const float*)d_in[14];
  const float* kB     = (const float*)d_in[15];

  float* Xout = (float*)d_out;
  float* Tout = (float*)d_out + (size_t)BB * NN * CC;

  char* ws = (char*)d_ws;
  size_t off = 0;
  auto alloc_f = [&](size_t n) { float* pp = (float*)(ws + off); off += n * 4; return pp; };
  float* Tbuf   = alloc_f(524288);
  float* kqbuf  = alloc_f(524288);
  float* Tdash  = alloc_f(524288);
  float* rbuf   = alloc_f(1024);
  float* biaskq = alloc_f(1024);
  float* Mloc   = alloc_f(8192);
  float* Sloc   = alloc_f(8192);
  auto alloc_h = [&](size_t n) { unsigned short* pp = (unsigned short*)(ws + off); off += n * 2; return pp; };
  unsigned short* Tp     = alloc_h(8388608);   // [B][16][L][C] bf16
  unsigned short* Tbf    = alloc_h(524288);
  unsigned short* Tdbf   = alloc_h(524288);
  unsigned short* Hbf    = alloc_h(524288);
  unsigned short* Toutbf = alloc_h(524288);
  unsigned short* Tkbf   = alloc_h(524288);
  unsigned short* Gtbf   = alloc_h(524288);
  unsigned short* WkqT   = alloc_h(1048576);
  unsigned short* f1WT   = alloc_h(1048576);
  unsigned short* f2WT   = alloc_h(1048576);
  unsigned short* kWT    = alloc_h(1048576);
  unsigned short* qWbf   = alloc_h(1048576);
  unsigned short* tokWT  = alloc_h(16384);
  (void)ws_size; (void)in_sizes; (void)n_in; (void)out_size;

  wprep<<<dim3(32, 32, 6), dim3(32, 8), 0, stream>>>(keyW, queryW, f1W, f2W, kW, qW,
                                                     tokW, keyB, queryB,
                                                     WkqT, f1WT, f2WT, kWT, qWbf, tokWT, biaskq);
  tok_fused<<<dim3(16, 32), 512, 0, stream>>>(X, tokWT, tokB, Tp, Mloc, Sloc);
  tmerge<<<256, 256, 0, stream>>>(Tp, Mloc, Sloc, Tbuf, Tbf);
  gemm32x64<0,1,0,1,0><<<dim3(16, 16), 256, 0, stream>>>(Tbf, WkqT, biaskq, nullptr, kqbuf, nullptr);
  scores_tdash<<<dim3(8, 32), 256, 0, stream>>>(kqbuf, Tbuf, Tdash, Tdbf);
  gemm32x64<1,1,0,0,1><<<dim3(16, 16), 256, 0, stream>>>(Tdbf, f1WT, f1B, nullptr, nullptr, Hbf);
  gemm32x64<0,1,1,1,1><<<dim3(16, 16), 256, 0, stream>>>(Hbf, f2WT, f2B, Tdash, Tout, Toutbf);
  gemm32x64<0,1,0,0,1><<<dim3(16, 16), 256, 0, stream>>>(Toutbf, kWT, kB, nullptr, nullptr, Tkbf);
  r_kernel<<<128, 256, 0, stream>>>(Tkbf, qB, rbuf);
  gemm32x64<0,0,0,0,1><<<dim3(16, 16), 256, 0, stream>>>(Tkbf, qWbf, nullptr, nullptr, nullptr, Gtbf);
  sim_out_kernel<<<dim3(16, 32), 512, 0, stream>>>(X, Gtbf, rbuf, Tout, Xout);
}

// Round 13
// 175.864 us; speedup vs baseline: 1.1738x; 1.1738x over previous
//
#include <hip/hip_runtime.h>
#include <hip/hip_bf16.h>
#include <stdint.h>

#define BB 32
#define NN 1024
#define CC 1024
#define LL 16

typedef __attribute__((ext_vector_type(4))) float f32x4;
typedef __attribute__((ext_vector_type(8))) short short8;
typedef __attribute__((ext_vector_type(4))) unsigned short ushort4v;

__device__ __forceinline__ unsigned short f2bf(float f) {
  union { float f; unsigned u; } v; v.f = f;
  unsigned r = v.u + 0x7FFF + ((v.u >> 16) & 1);
  return (unsigned short)(r >> 16);
}
__device__ __forceinline__ float bf2f(unsigned short h) {
  union { unsigned u; float f; } v; v.u = ((unsigned)h) << 16; return v.f;
}
__device__ __forceinline__ short8 cvt8(f32x4 a, f32x4 b) {
  short8 r;
  r[0] = (short)f2bf(a[0]); r[1] = (short)f2bf(a[1]);
  r[2] = (short)f2bf(a[2]); r[3] = (short)f2bf(a[3]);
  r[4] = (short)f2bf(b[0]); r[5] = (short)f2bf(b[1]);
  r[6] = (short)f2bf(b[2]); r[7] = (short)f2bf(b[3]);
  return r;
}

// ---------------- weight prep: transpose->bf16 (+ tokW^T, bias pack at z=5) ----------------
__global__ __launch_bounds__(256) void wprep(
    const float* __restrict__ keyW, const float* __restrict__ queryW,
    const float* __restrict__ f1W, const float* __restrict__ f2W,
    const float* __restrict__ kW, const float* __restrict__ qW,
    const float* __restrict__ tokW, const float* __restrict__ keyb,
    const float* __restrict__ queryb,
    unsigned short* __restrict__ WkqT, unsigned short* __restrict__ f1WT,
    unsigned short* __restrict__ f2WT, unsigned short* __restrict__ kWT,
    unsigned short* __restrict__ qWbf, unsigned short* __restrict__ tokWT,
    float* __restrict__ biaskq)
{
  int z = blockIdx.z;
  int tx = threadIdx.x, ty = threadIdx.y;
  if (z == 5) {
    int gid = (blockIdx.y * 32 + blockIdx.x) * 256 + ty * 32 + tx;
    if (gid < 16384) {
      int l = gid >> 10, c = gid & 1023;
      tokWT[gid] = f2bf(tokW[c * 16 + l]);
    } else if (gid < 17408) {
      int i = gid - 16384;
      biaskq[i] = (i < 512) ? keyb[i] : queryb[i - 512];
    }
    return;
  }
  if (z == 4) {
#pragma unroll
    for (int i = 0; i < 4; ++i) {
      int row = blockIdx.y * 32 + ty + 8 * i;
      int col = blockIdx.x * 32 + tx;
      qWbf[row * 1024 + col] = f2bf(qW[row * 1024 + col]);
    }
    return;
  }
  __shared__ float tile[32][33];
  int j0 = blockIdx.x * 32, k0 = blockIdx.y * 32;
  const float* src = (z == 1) ? f1W : (z == 2) ? f2W : kW;
#pragma unroll
  for (int i = 0; i < 4; ++i) {
    int k = k0 + ty + 8 * i;
    int j = j0 + tx;
    float v;
    if (z == 0) v = (j < 512) ? keyW[k * 512 + j] : queryW[k * 512 + (j - 512)];
    else        v = src[k * 1024 + j];
    tile[ty + 8 * i][tx] = v;
  }
  __syncthreads();
  unsigned short* dst = (z == 0) ? WkqT : (z == 1) ? f1WT : (z == 2) ? f2WT : kWT;
#pragma unroll
  for (int i = 0; i < 4; ++i) {
    int j = j0 + ty + 8 * i;
    dst[j * 1024 + k0 + tx] = f2bf(tile[tx][ty + 8 * i]);
  }
}

// ---------------- fused tokenizer: direct-frag proj MFMA + chunk softmax + partial T ----------------
__global__ __launch_bounds__(256) void tok_fused(
    const float* __restrict__ X, const unsigned short* __restrict__ tokWT,
    const float* __restrict__ tokB, unsigned short* __restrict__ Tp,
    float* __restrict__ Mloc, float* __restrict__ Sloc)
{
  __shared__ float E[64][16];
  __shared__ float redm[4][16];
  __shared__ float reds[4][16];
  int tid = threadIdx.x, wid = tid >> 6, lane = tid & 63;
  int lr = lane & 15, hi = lane >> 4;
  int b = blockIdx.y, ch = blockIdx.x;
  int pix0 = b * 1024 + ch * 64;
  // phase 1: S = X @ tokW^T via direct-fragment MFMA (wave handles 16 rows)
  const float* Ar = X + (size_t)(pix0 + wid * 16 + lr) * 1024 + hi * 8;
  const unsigned short* Br = tokWT + lr * 1024 + hi * 8;
  f32x4 acc = (f32x4)0.f;
#pragma unroll 8
  for (int k0 = 0; k0 < 1024; k0 += 32) {
    f32x4 x0 = *(const f32x4*)(Ar + k0);
    f32x4 x1 = *(const f32x4*)(Ar + k0 + 4);
    short8 bfrag = *(const short8*)(Br + k0);
    acc = __builtin_amdgcn_mfma_f32_16x16x32_bf16(cvt8(x0, x1), bfrag, acc, 0, 0, 0);
  }
  // chunk-local softmax partials per column l=lr; lane holds rows wid*16+hi*4+rr
  float tb = tokB[lr];
  float sv[4];
#pragma unroll
  for (int rr = 0; rr < 4; ++rr) sv[rr] = acc[rr] + tb;
  float pm = fmaxf(fmaxf(sv[0], sv[1]), fmaxf(sv[2], sv[3]));
  pm = fmaxf(pm, __shfl_xor(pm, 16));
  pm = fmaxf(pm, __shfl_xor(pm, 32));
  if (hi == 0) redm[wid][lr] = pm;
  __syncthreads();
  float m = fmaxf(fmaxf(redm[0][lr], redm[1][lr]), fmaxf(redm[2][lr], redm[3][lr]));
  float ev[4]; float ps = 0.f;
#pragma unroll
  for (int i = 0; i < 4; ++i) { ev[i] = __expf(sv[i] - m); ps += ev[i]; }
  ps += __shfl_xor(ps, 16); ps += __shfl_xor(ps, 32);
  if (hi == 0) reds[wid][lr] = ps;
#pragma unroll
  for (int rr = 0; rr < 4; ++rr)
    E[wid * 16 + hi * 4 + rr][lr] = ev[rr];
  __syncthreads();
  if (tid < 16) {
    float sl = reds[0][tid] + reds[1][tid] + reds[2][tid] + reds[3][tid];
    Mloc[(b * 16 + ch) * 16 + tid] = m;
    Sloc[(b * 16 + ch) * 16 + tid] = sl;
  }
  // phase 2: partial T[l][c] = sum_n E[n][l] * X[n][c]  (chunk L2/L3-hot)
  f32x4 a16[16];
#pragma unroll
  for (int l = 0; l < 16; ++l) a16[l] = (f32x4)0.f;
  const float* xp = X + (size_t)pix0 * 1024 + tid * 4;
  for (int n0 = 0; n0 < 64; n0 += 8) {
    f32x4 xv[8];
#pragma unroll
    for (int i = 0; i < 8; ++i) xv[i] = *(const f32x4*)(xp + (size_t)(n0 + i) * 1024);
#pragma unroll
    for (int i = 0; i < 8; ++i) {
      const f32x4* ar = (const f32x4*)&E[n0 + i][0];
      f32x4 a0 = ar[0], a1 = ar[1], a2 = ar[2], a3 = ar[3];
      f32x4 x0 = xv[i];
      a16[0]  += a0[0]*x0; a16[1]  += a0[1]*x0; a16[2]  += a0[2]*x0; a16[3]  += a0[3]*x0;
      a16[4]  += a1[0]*x0; a16[5]  += a1[1]*x0; a16[6]  += a1[2]*x0; a16[7]  += a1[3]*x0;
      a16[8]  += a2[0]*x0; a16[9]  += a2[1]*x0; a16[10] += a2[2]*x0; a16[11] += a2[3]*x0;
      a16[12] += a3[0]*x0; a16[13] += a3[1]*x0; a16[14] += a3[2]*x0; a16[15] += a3[3]*x0;
    }
  }
  unsigned short* op = Tp + ((size_t)(b * 16 + ch) * 16) * 1024 + tid * 4;
#pragma unroll
  for (int l = 0; l < 16; ++l) {
    f32x4 s = a16[l];
    ushort4v h; h[0]=f2bf(s[0]); h[1]=f2bf(s[1]); h[2]=f2bf(s[2]); h[3]=f2bf(s[3]);
    *(ushort4v*)(op + (size_t)l * 1024) = h;
  }
}

// ---------------- merge 16 chunk partials with online-softmax rescale ----------------
__global__ __launch_bounds__(256) void tmerge(
    const unsigned short* __restrict__ Tp, const float* __restrict__ Mloc,
    const float* __restrict__ Sloc, float* __restrict__ T,
    unsigned short* __restrict__ Tbf)
{
  int tid = threadIdx.x;
  int g = blockIdx.x * 2 + (tid >> 7);    // token row in [0,512)
  int b = g >> 4, l = g & 15;
  int j = tid & 127;
  float M = -1e30f;
#pragma unroll
  for (int ch = 0; ch < 16; ++ch) M = fmaxf(M, Mloc[(b * 16 + ch) * 16 + l]);
  float w[16]; float denom = 0.f;
#pragma unroll
  for (int ch = 0; ch < 16; ++ch) {
    w[ch] = __expf(Mloc[(b * 16 + ch) * 16 + l] - M);
    denom += w[ch] * Sloc[(b * 16 + ch) * 16 + l];
  }
  float inv = 1.f / denom;
  float o[8];
#pragma unroll
  for (int t = 0; t < 8; ++t) o[t] = 0.f;
#pragma unroll
  for (int ch = 0; ch < 16; ++ch) {
    const unsigned short* p = Tp + ((size_t)((b * 16 + ch) * 16 + l)) * 1024 + j * 8;
    short8 v = *(const short8*)p;
    float wc = w[ch];
#pragma unroll
    for (int t = 0; t < 8; ++t) o[t] += wc * bf2f((unsigned short)v[t]);
  }
  f32x4 o0, o1; short8 hb;
#pragma unroll
  for (int t = 0; t < 4; ++t) {
    float x0 = o[t] * inv, x1 = o[4 + t] * inv;
    o0[t] = x0; o1[t] = x1;
    hb[t] = (short)f2bf(x0); hb[4 + t] = (short)f2bf(x1);
  }
  *(f32x4*)(T + (size_t)g * 1024 + j * 8) = o0;
  *(f32x4*)(T + (size_t)g * 1024 + j * 8 + 4) = o1;
  *(short8*)(Tbf + (size_t)g * 1024 + j * 8) = hb;
}

// ---------------- NT bf16 GEMM, M=512, Nn=1024, K=1024, 32x64 tiles ----------------
template<int RELU, int HAS_BIAS, int HAS_RES, int STORE_F32, int STORE_BF16>
__global__ __launch_bounds__(256) void gemm32x64(
    const unsigned short* __restrict__ A, const unsigned short* __restrict__ Bm,
    const float* __restrict__ bias, const float* __restrict__ res,
    float* __restrict__ outF, unsigned short* __restrict__ outB)
{
  const int K = 1024;
  __shared__ __align__(16) char sh[12288];   // As 4KB | Bs 8KB, XOR-swizzled rows of 128B
  char* Asp = sh;
  char* Bsp = sh + 4096;
  int tid = threadIdx.x, wid = tid >> 6, lane = tid & 63;
  int lr = lane & 15, hi = lane >> 4;
  int m0 = blockIdx.x * 32, n0 = blockIdx.y * 64;
  int arow = tid >> 3, acol = (tid & 7) * 8;   // A stage: 32x64
  int brow = tid >> 2, bcol = (tid & 3) * 16;  // B stage: 64x64
  const unsigned short* Ap = A + (size_t)(m0 + arow) * K + acol;
  const unsigned short* Bp = Bm + (size_t)(n0 + brow) * K + bcol;
  int aw  = arow * 128 + (((acol * 2) ^ ((arow & 7) << 4)));
  int bw0 = brow * 128 + (((bcol * 2) ^ ((brow & 7) << 4)));
  int bw1 = brow * 128 + ((((bcol * 2) + 16) ^ ((brow & 7) << 4)));
  short8 aR[2]; short8 bR[2][2];
  aR[0]    = *(const short8*)(Ap);
  bR[0][0] = *(const short8*)(Bp);
  bR[0][1] = *(const short8*)(Bp + 8);
  aR[1]    = *(const short8*)(Ap + 64);
  bR[1][0] = *(const short8*)(Bp + 64);
  bR[1][1] = *(const short8*)(Bp + 72);
  f32x4 acc[2];
  acc[0] = (f32x4)0.f; acc[1] = (f32x4)0.f;
  int wm = (wid >> 1) * 16, wn = (wid & 1) * 32;
  int arb = (wm + lr) * 128, arx = ((wm + lr) & 7) << 4;
  for (int s = 0; s < 16; ++s) {
    __syncthreads();
    *(short8*)(Asp + aw)  = aR[s & 1];
    *(short8*)(Bsp + bw0) = bR[s & 1][0];
    *(short8*)(Bsp + bw1) = bR[s & 1][1];
    __syncthreads();
    if (s + 2 < 16) {
      int k0 = (s + 2) * 64;
      aR[s & 1]    = *(const short8*)(Ap + k0);
      bR[s & 1][0] = *(const short8*)(Bp + k0);
      bR[s & 1][1] = *(const short8*)(Bp + k0 + 8);
    }
#pragma unroll
    for (int kk = 0; kk < 2; ++kk) {
      short8 af = *(const short8*)(Asp + arb + (((kk * 64 + hi * 16) ^ arx)));
#pragma unroll
      for (int sn = 0; sn < 2; ++sn) {
        int br = wn + sn * 16 + lr;
        short8 bf = *(const short8*)(Bsp + br * 128 + (((kk * 64 + hi * 16) ^ ((br & 7) << 4))));
        acc[sn] = __builtin_amdgcn_mfma_f32_16x16x32_bf16(af, bf, acc[sn], 0, 0, 0);
      }
    }
  }
  int row0 = m0 + wm + hi * 4;
#pragma unroll
  for (int sn = 0; sn < 2; ++sn) {
    int col = n0 + wn + sn * 16 + lr;
    float bv_ = HAS_BIAS ? bias[col] : 0.f;
#pragma unroll
    for (int rr = 0; rr < 4; ++rr) {
      float x = acc[sn][rr] + bv_;
      if (RELU) x = fmaxf(x, 0.f);
      size_t idx = (size_t)(row0 + rr) * 1024 + col;
      if (HAS_RES) x += res[idx];
      if (STORE_F32) outF[idx] = x;
      if (STORE_BF16) outB[idx] = f2bf(x);
    }
  }
}

// ---------------- token self-attn: scores + softmax + T_dash (c-split 8) ----------------
__global__ __launch_bounds__(256) void scores_tdash(
    const float* __restrict__ kq, const float* __restrict__ T,
    float* __restrict__ Tdash, unsigned short* __restrict__ Tdbf)
{
  int cs = blockIdx.x, b = blockIdx.y;
  int c0 = cs * 128;
  __shared__ float Ts[16][128];
  int tid = threadIdx.x, lane = tid & 63;
#pragma unroll
  for (int i = 0; i < 2; ++i) {
    int fi = tid + 256 * i;            // f4 over 512
    int rrow = fi >> 5, c4 = (fi & 31) * 4;
    *(f32x4*)&Ts[rrow][c4] = *(const f32x4*)&T[((size_t)b * 16 + rrow) * 1024 + c0 + c4];
  }
  __syncthreads();
  int l = tid >> 4, m = tid & 15;
  const float* krow = kq + ((size_t)b * 16 + l) * 1024;
  const float* qrow = kq + ((size_t)b * 16 + m) * 1024 + 512;
  float s = 0.f;
#pragma unroll 8
  for (int d = 0; d < 512; d += 4) {
    f32x4 kv = *(const f32x4*)(krow + d);
    f32x4 qv = *(const f32x4*)(qrow + d);
    s += kv[0]*qv[0] + kv[1]*qv[1] + kv[2]*qv[2] + kv[3]*qv[3];
  }
  float mx = s;
  mx = fmaxf(mx, __shfl_xor(mx, 1)); mx = fmaxf(mx, __shfl_xor(mx, 2));
  mx = fmaxf(mx, __shfl_xor(mx, 4)); mx = fmaxf(mx, __shfl_xor(mx, 8));
  float e = __expf(s - mx);
  float sum = e;
  sum += __shfl_xor(sum, 1); sum += __shfl_xor(sum, 2);
  sum += __shfl_xor(sum, 4); sum += __shfl_xor(sum, 8);
  float pv = e / sum;
  float pl[16];
#pragma unroll
  for (int i = 0; i < 16; ++i) pl[i] = __shfl(pv, (lane & 48) + i);
  float* od = Tdash + ((size_t)b * 16 + l) * 1024 + c0;
  unsigned short* ob = Tdbf + ((size_t)b * 16 + l) * 1024 + c0;
#pragma unroll
  for (int h = 0; h < 2; ++h) {
    int c = m * 8 + h * 4;
    f32x4 o = *(const f32x4*)&Ts[l][c];
#pragma unroll
    for (int mm = 0; mm < 16; ++mm) {
      f32x4 tv = *(const f32x4*)&Ts[mm][c];
      o += pl[mm] * tv;
    }
    *(f32x4*)(od + c) = o;
    ushort4v hh; hh[0]=f2bf(o[0]); hh[1]=f2bf(o[1]); hh[2]=f2bf(o[2]); hh[3]=f2bf(o[3]);
    *(ushort4v*)(ob + c) = hh;
  }
}

// ---------------- r[b,l] = q_b . Tk[b,l,:] ----------------
__global__ __launch_bounds__(256) void r_kernel(
    const unsigned short* __restrict__ Tkbf, const float* __restrict__ qb,
    float* __restrict__ r)
{
  int row = blockIdx.x * 4 + (threadIdx.x >> 6);
  int lane = threadIdx.x & 63;
  const unsigned short* p = Tkbf + (size_t)row * CC;
  float s = 0.f;
#pragma unroll
  for (int h = 0; h < 2; ++h) {
    int d0 = lane * 8 + h * 512;
    short8 v = *(const short8*)&p[d0];
#pragma unroll
    for (int jj = 0; jj < 8; ++jj)
      s += bf2f((unsigned short)v[jj]) * qb[d0 + jj];
  }
#pragma unroll
  for (int msk = 32; msk >= 1; msk >>= 1) s += __shfl_xor(s, msk);
  if (lane == 0) r[row] = s;
}

// ---------------- fused sim + out: direct-frag MFMA, P in LDS, X_out = X + P@T_out ----------------
__global__ __launch_bounds__(256) void sim_out_kernel(
    const float* __restrict__ X, const unsigned short* __restrict__ Gt,
    const float* __restrict__ rbias, const float* __restrict__ Tout,
    float* __restrict__ Xout)
{
  __shared__ float Ps[64][16];
  int tid = threadIdx.x, wid = tid >> 6, lane = tid & 63;
  int lr = lane & 15, hi = lane >> 4;
  int b = blockIdx.y;
  int pix0 = b * 1024 + blockIdx.x * 64;
  const float* Ar = X + (size_t)(pix0 + wid * 16 + lr) * 1024 + hi * 8;
  const unsigned short* Br = Gt + (size_t)b * 16384 + lr * 1024 + hi * 8;
  f32x4 acc = (f32x4)0.f;
#pragma unroll 8
  for (int k0 = 0; k0 < 1024; k0 += 32) {
    f32x4 x0 = *(const f32x4*)(Ar + k0);
    f32x4 x1 = *(const f32x4*)(Ar + k0 + 4);
    short8 bfrag = *(const short8*)(Br + k0);
    acc = __builtin_amdgcn_mfma_f32_16x16x32_bf16(cvt8(x0, x1), bfrag, acc, 0, 0, 0);
  }
  // in-register softmax over l (16-lane groups), P -> LDS
  float bv = rbias[b * 16 + lr];
  int prow = wid * 16 + hi * 4;
#pragma unroll
  for (int rr = 0; rr < 4; ++rr) {
    float vv = acc[rr] + bv;
    float mx = vv;
    mx = fmaxf(mx, __shfl_xor(mx, 1)); mx = fmaxf(mx, __shfl_xor(mx, 2));
    mx = fmaxf(mx, __shfl_xor(mx, 4)); mx = fmaxf(mx, __shfl_xor(mx, 8));
    float e = __expf(vv - mx);
    float ss = e;
    ss += __shfl_xor(ss, 1); ss += __shfl_xor(ss, 2);
    ss += __shfl_xor(ss, 4); ss += __shfl_xor(ss, 8);
    Ps[prow + rr][lr] = e / ss;
  }
  __syncthreads();
  // phase 2: X_out = X + P @ T_out, T_out column-slice in registers
  int c4 = tid * 4;
  f32x4 tsr[16];
#pragma unroll
  for (int l = 0; l < 16; ++l)
    tsr[l] = *(const f32x4*)&Tout[((size_t)b * 16 + l) * 1024 + c4];
  const float* xp = X + (size_t)pix0 * 1024 + c4;
  float* op = Xout + (size_t)pix0 * 1024 + c4;
#pragma unroll 2
  for (int n = 0; n < 64; ++n) {
    f32x4 xv = *(const f32x4*)(xp + (size_t)n * 1024);
    const f32x4* pr = (const f32x4*)&Ps[n][0];
    f32x4 p0 = pr[0], p1 = pr[1], p2 = pr[2], p3 = pr[3];
    f32x4 o = xv;
    o += p0[0]*tsr[0];  o += p0[1]*tsr[1];  o += p0[2]*tsr[2];  o += p0[3]*tsr[3];
    o += p1[0]*tsr[4];  o += p1[1]*tsr[5];  o += p1[2]*tsr[6];  o += p1[3]*tsr[7];
    o += p2[0]*tsr[8];  o += p2[1]*tsr[9];  o += p2[2]*tsr[10]; o += p2[3]*tsr[11];
    o += p3[0]*tsr[12]; o += p3[1]*tsr[13]; o += p3[2]*tsr[14]; o += p3[3]*tsr[15];
    __builtin_nontemporal_store(o, (f32x4*)(op + (size_t)n * 1024));
  }
}

extern "C" void kernel_launch(void* const* d_in, const int* in_sizes, int n_in,
                              void* d_out, int out_size, void* d_ws, size_t ws_size,
                              hipStream_t stream)
{
  const float* X      = (const float*)d_in[0];
  const float* tokW   = (const float*)d_in[2];
  const float* tokB   = (const float*)d_in[3];
  const float* keyW   = (const float*)d_in[4];
  const float* keyB   = (const float*)d_in[5];
  const float* queryW = (const float*)d_in[6];
  const float* queryB = (const float*)d_in[7];
  const float* f1W    = (const float*)d_in[8];
  const float* f1B    = (const float*)d_in[9];
  const float* f2W    = (const float*)d_in[10];
  const float* f2B    = (const float*)d_in[11];
  const float* qW     = (const float*)d_in[12];
  const float* qB     = (const float*)d_in[13];
  const float* kW     = (const float*)d_in[14];
  const float* kB     = (const float*)d_in[15];

  float* Xout = (float*)d_out;
  float* Tout = (float*)d_out + (size_t)BB * NN * CC;

  char* ws = (char*)d_ws;
  size_t off = 0;
  auto alloc_f = [&](size_t n) { float* pp = (float*)(ws + off); off += n * 4; return pp; };
  float* Tbuf   = alloc_f(524288);
  float* kqbuf  = alloc_f(524288);
  float* Tdash  = alloc_f(524288);
  float* rbuf   = alloc_f(1024);
  float* biaskq = alloc_f(1024);
  float* Mloc   = alloc_f(8192);
  float* Sloc   = alloc_f(8192);
  auto alloc_h = [&](size_t n) { unsigned short* pp = (unsigned short*)(ws + off); off += n * 2; return pp; };
  unsigned short* Tp     = alloc_h(8388608);   // [B][16][L][C] bf16
  unsigned short* Tbf    = alloc_h(524288);
  unsigned short* Tdbf   = alloc_h(524288);
  unsigned short* Hbf    = alloc_h(524288);
  unsigned short* Toutbf = alloc_h(524288);
  unsigned short* Tkbf   = alloc_h(524288);
  unsigned short* Gtbf   = alloc_h(524288);
  unsigned short* WkqT   = alloc_h(1048576);
  unsigned short* f1WT   = alloc_h(1048576);
  unsigned short* f2WT   = alloc_h(1048576);
  unsigned short* kWT    = alloc_h(1048576);
  unsigned short* qWbf   = alloc_h(1048576);
  unsigned short* tokWT  = alloc_h(16384);
  (void)ws_size; (void)in_sizes; (void)n_in; (void)out_size;

  wprep<<<dim3(32, 32, 6), dim3(32, 8), 0, stream>>>(keyW, queryW, f1W, f2W, kW, qW,
                                                     tokW, keyB, queryB,
                                                     WkqT, f1WT, f2WT, kWT, qWbf, tokWT, biaskq);
  tok_fused<<<dim3(16, 32), 256, 0, stream>>>(X, tokWT, tokB, Tp, Mloc, Sloc);
  tmerge<<<256, 256, 0, stream>>>(Tp, Mloc, Sloc, Tbuf, Tbf);
  gemm32x64<0,1,0,1,0><<<dim3(16, 16), 256, 0, stream>>>(Tbf, WkqT, biaskq, nullptr, kqbuf, nullptr);
  scores_tdash<<<dim3(8, 32), 256, 0, stream>>>(kqbuf, Tbuf, Tdash, Tdbf);
  gemm32x64<1,1,0,0,1><<<dim3(16, 16), 256, 0, stream>>>(Tdbf, f1WT, f1B, nullptr, nullptr, Hbf);
  gemm32x64<0,1,1,1,1><<<dim3(16, 16), 256, 0, stream>>>(Hbf, f2WT, f2B, Tdash, Tout, Toutbf);
  gemm32x64<0,1,0,0,1><<<dim3(16, 16), 256, 0, stream>>>(Toutbf, kWT, kB, nullptr, nullptr, Tkbf);
  r_kernel<<<128, 256, 0, stream>>>(Tkbf, qB, rbuf);
  gemm32x64<0,0,0,0,1><<<dim3(16, 16), 256, 0, stream>>>(Tkbf, qWbf, nullptr, nullptr, nullptr, Gtbf);
  sim_out_kernel<<<dim3(16, 32), 256, 0, stream>>>(X, Gtbf, rbuf, Tout, Xout);
}